// Round 11
// baseline (150.286 us; speedup 1.0000x reference)
//
#include <hip/hip_runtime.h>
#include <hip/hip_bf16.h>

#define NB   32
#define LQ   2048
#define LK   2048
#define EPSF 1e-5f
// p = exp2(dot(q_scaled, k) - C_L2E); scale = log2(e)/sqrt(20), C = 5*log2(e)
#define SCALE_L2E 0.32260327f
#define C_L2E     7.2134752f

// mask encodings (detected per-block from byte signatures)
#define MASK_I32  0
#define MASK_B8   1
#define MASK_BF16 2
#define MASK_F32  3

typedef __attribute__((ext_vector_type(8))) short  short8;   // 8 bf16 = 4 VGPR
typedef __attribute__((ext_vector_type(4))) float  floatx4;  // MFMA C/D

__device__ __forceinline__ unsigned short f2b(float f) {
    union { float f; unsigned int i; } c; c.f = f;
    unsigned int x = c.i;
    return (unsigned short)((x + 0x7FFFu + ((x >> 16) & 1u)) >> 16);  // RNE
}
// packed f32x2 -> bf16x2 (v_cvt_pk_bf16_f32 on gfx950, RNE)
__device__ __forceinline__ unsigned int pkbf(float a, float b) {
    __hip_bfloat162 h = __float22bfloat162_rn(make_float2(a, b));
    union { __hip_bfloat162 h; unsigned int u; } c; c.h = h; return c.u;
}

__device__ __forceinline__ int mask_nz(const void* m, int g, int enc) {
    switch (enc) {
        case MASK_B8:   return ((const unsigned char*)m)[g]  != 0;
        case MASK_BF16: return ((const unsigned short*)m)[g] != 0;
        case MASK_F32:  return ((const unsigned int*)m)[g]   != 0;
        default:        return ((const int*)m)[g]            != 0;
    }
}

// ---------------------------------------------------------------------------
// Kernel 1 (unchanged, verified): k = LN(keys @ Wk^T), v = vals @ Wv^T.
// kbf [B][2048][32] bf16 (20 real + 12 zero); vTb [B][32][2048] bf16.
// ---------------------------------------------------------------------------
__global__ __launch_bounds__(256) void proj_kv_kernel(
    const float4* __restrict__ vals,
    const float4* __restrict__ keys,
    const void*   __restrict__ key_mask,
    const float4* __restrict__ Wv,
    const float4* __restrict__ Wk,
    const float*  __restrict__ gk,
    const float*  __restrict__ bk,
    int*            __restrict__ counts,
    unsigned short* __restrict__ kbf,
    unsigned short* __restrict__ vTb)
{
    __shared__ float smem[1704];
    __shared__ int sc[3];
    float* sWv = smem;
    float* sWk = smem + 1024;
    float* sgk = smem + 1664;
    float* sbk = smem + 1684;
    const int tid = threadIdx.x;
    if (tid < 3) sc[tid] = 0;
    __syncthreads();

    ((float4*)sWv)[tid] = Wv[tid];
    if (tid < 160) ((float4*)sWk)[tid] = Wk[tid];
    if (tid < 20) sgk[tid] = gk[tid];
    if (tid >= 32 && tid < 52) sbk[tid - 32] = bk[tid - 32];
    {
        const unsigned char* mbytes = (const unsigned char*)key_mask;
        int l0 = 0, l1 = 0, l2 = 0;
        for (int i = tid; i < 1024; i += 256) {
            const unsigned char mb = mbytes[i];
            if ((i & 3) == 1 && mb == 0x3Fu) l0++;
            if ((i & 3) == 3 && mb == 0x3Fu) l1++;
            if ((i & 1) == 1 && mb == 0x01u) l2++;
        }
        if (l0) atomicAdd(&sc[0], l0);
        if (l1) atomicAdd(&sc[1], l1);
        if (l2) atomicAdd(&sc[2], l2);
    }
    __syncthreads();
    const int enc = sc[0] ? MASK_BF16 : (sc[1] ? MASK_F32 : (sc[2] ? MASK_B8 : MASK_I32));

    const int g = blockIdx.x * 256 + tid;
    const int b = g >> 11;
    const int lane = tid & 63;

    const int valid = mask_nz(key_mask, g, enc) ? 0 : 1;
    const unsigned long long mb = __ballot(valid);
    const int cnt = __popcll(mb);
    int base = 0;
    if (lane == 0) base = atomicAdd(&counts[b], cnt);
    base = __shfl(base, 0);
    const int slot = base + __popcll(mb & ((1ull << lane) - 1ull));

    float x[32];

    {   // keys -> k proj -> LN -> bf16 padded store
        const float4* kp = keys + (size_t)g * 8;
        #pragma unroll
        for (int t = 0; t < 8; ++t) {
            float4 u = kp[t];
            x[t*4+0] = u.x; x[t*4+1] = u.y; x[t*4+2] = u.z; x[t*4+3] = u.w;
        }
        const float4* wk4 = (const float4*)sWk;
        float kv[20];
        #pragma unroll
        for (int c = 0; c < 20; ++c) {
            float s = 0.f;
            #pragma unroll
            for (int i = 0; i < 8; ++i) {
                float4 ww = wk4[c * 8 + i];
                s = fmaf(x[i*4+0], ww.x, s); s = fmaf(x[i*4+1], ww.y, s);
                s = fmaf(x[i*4+2], ww.z, s); s = fmaf(x[i*4+3], ww.w, s);
            }
            kv[c] = s;
        }
        float m = 0.f;
        #pragma unroll
        for (int c = 0; c < 20; ++c) m += kv[c];
        m *= (1.f / 20.f);
        float v = 0.f;
        #pragma unroll
        for (int c = 0; c < 20; ++c) { float d = kv[c] - m; v += d * d; }
        v *= (1.f / 20.f);
        const float r = rsqrtf(v + EPSF);
        if (valid) {
            unsigned int u[16];
            #pragma unroll
            for (int j = 0; j < 10; ++j) {
                const float t0 = (kv[2*j]   - m) * r * sgk[2*j]   + sbk[2*j];
                const float t1 = (kv[2*j+1] - m) * r * sgk[2*j+1] + sbk[2*j+1];
                u[j] = pkbf(t0, t1);
            }
            #pragma unroll
            for (int j = 10; j < 16; ++j) u[j] = 0u;
            uint4* dst = (uint4*)kbf + (size_t)(b * 2048 + slot) * 4;
            #pragma unroll
            for (int j = 0; j < 4; ++j)
                dst[j] = make_uint4(u[j*4], u[j*4+1], u[j*4+2], u[j*4+3]);
        }
    }

    {   // vals -> v proj -> transposed bf16 store
        const float4* vp = vals + (size_t)g * 8;
        #pragma unroll
        for (int t = 0; t < 8; ++t) {
            float4 u = vp[t];
            x[t*4+0] = u.x; x[t*4+1] = u.y; x[t*4+2] = u.z; x[t*4+3] = u.w;
        }
        if (valid) {
            const float4* wv4 = (const float4*)sWv;
            #pragma unroll
            for (int o = 0; o < 32; ++o) {
                float s = 0.f;
                #pragma unroll
                for (int i = 0; i < 8; ++i) {
                    float4 ww = wv4[o * 8 + i];
                    s = fmaf(x[i*4+0], ww.x, s); s = fmaf(x[i*4+1], ww.y, s);
                    s = fmaf(x[i*4+2], ww.z, s); s = fmaf(x[i*4+3], ww.w, s);
                }
                vTb[((size_t)b * 32 + o) * 2048 + slot] = f2b(s);
            }
        }
    }
}

// ---------------------------------------------------------------------------
// Kernel 2: MFMA flash attention (structure = R10; ONE change: launch_bounds
// min-occupancy 6 waves/EU -> caps VGPR at 85 so the 3rd block/CU fits:
// LDS 53760*3 = 161280 <= 163840 and 3*512 = 1536 <= 2048 threads. 24
// waves/CU (vs 16) overlap barrier drains across blocks — the measured gap
// between the ~14 us LDS floor and ~38 us actual is barrier/latency skew.
// ---------------------------------------------------------------------------
__global__ __launch_bounds__(512, 6) void attn_kernel(
    const unsigned short* __restrict__ kbf,   // [B][2048][32] bf16
    const unsigned short* __restrict__ vTb,   // [B][32][2048] bf16
    const int*    __restrict__ counts,
    const float4* __restrict__ ques,          // [B*LQ*32] f32
    const float4* __restrict__ Wq,
    const float*  __restrict__ gq,
    const float*  __restrict__ bq,
    const float*  __restrict__ go,
    const float*  __restrict__ bo,
    float* __restrict__ out)
{
    __shared__ uint4 smem4[3360];             // 53760 B
    char*  smemB = (char*)smem4;
    float* smemF = (float*)smem4;

    const int tid  = threadIdx.x;
    const int w    = tid >> 6;                // 0..7
    const int lane = tid & 63;
    const int qcol = lane & 15;
    const int quad = lane >> 4;
    const int bb   = blockIdx.y;
    const int qbase = blockIdx.x * 128;

    // ---- prologue: Wq/gq/bq into sK region (floats 0..680)
    if (tid < 160) ((float4*)smemF)[tid] = Wq[tid];
    if (tid >= 192 && tid < 212) smemF[640 + tid - 192] = gq[tid - 192];
    if (tid >= 224 && tid < 244) smemF[660 + tid - 224] = bq[tid - 224];
    __syncthreads();

    // ---- q proj + LN + scale -> bf16 rows (20 real + 12 zero) in sPT region
    if (tid < 128) {
        const size_t grow = (size_t)bb * LQ + qbase + tid;
        float x[32];
        const float4* qp = ques + grow * 8;
        #pragma unroll
        for (int t = 0; t < 8; ++t) {
            float4 u = qp[t];
            x[t*4+0] = u.x; x[t*4+1] = u.y; x[t*4+2] = u.z; x[t*4+3] = u.w;
        }
        float qv[20];
        #pragma unroll
        for (int c = 0; c < 20; ++c) {
            float s = 0.f;
            #pragma unroll
            for (int i = 0; i < 32; ++i) s = fmaf(x[i], smemF[c*32 + i], s);
            qv[c] = s;
        }
        float m = 0.f;
        #pragma unroll
        for (int c = 0; c < 20; ++c) m += qv[c];
        m *= (1.f / 20.f);
        float v = 0.f;
        #pragma unroll
        for (int c = 0; c < 20; ++c) { float d = qv[c] - m; v += d * d; }
        v *= (1.f / 20.f);
        const float r = rsqrtf(v + EPSF);
        unsigned int u[16];
        #pragma unroll
        for (int j = 0; j < 10; ++j) {
            const float t0 = ((qv[2*j]   - m) * r * smemF[640+2*j]   + smemF[660+2*j])   * SCALE_L2E;
            const float t1 = ((qv[2*j+1] - m) * r * smemF[640+2*j+1] + smemF[660+2*j+1]) * SCALE_L2E;
            u[j] = pkbf(t0, t1);
        }
        #pragma unroll
        for (int j = 10; j < 16; ++j) u[j] = 0u;
        uint4* dst = (uint4*)(smemB + 18944 + tid * 80);
        #pragma unroll
        for (int j = 0; j < 4; ++j)
            dst[j] = make_uint4(u[j*4], u[j*4+1], u[j*4+2], u[j*4+3]);
    }
    __syncthreads();

    // loop-invariant B1 fragment: Q[q = w*16+qcol][k = quad*8..+7]
    const short8 qfrag = *(const short8*)(smemB + 18944 + (w*16 + qcol)*80 + quad*16);
    __syncthreads();   // sQ/Wq regions may now be overwritten

    const int nv = counts[bb];
    const int ntiles = (nv + 127) >> 7;
    const floatx4 cinit = { -C_L2E, -C_L2E, -C_L2E, -C_L2E };
    floatx4 oacc0 = {0.f, 0.f, 0.f, 0.f};
    floatx4 oacc1 = {0.f, 0.f, 0.f, 0.f};
    float lsum = 0.f;

    const unsigned short* kB = kbf + (size_t)bb * 2048 * 32;
    const unsigned short* vB = vTb + (size_t)bb * 32 * 2048;

    // staging thread mapping (512 threads, 16 B each for K and V^T)
    const int krow = tid >> 2, kq = tid & 3;     // K: 128 rows x 64 B
    const int vd   = tid >> 4, vkg = tid & 15;   // V^T: 32 dims x 256 B

    // prefetch tile 0
    uint4 pk, pv;
    if (ntiles > 0) {
        pk = *(const uint4*)(kB + (size_t)krow * 32 + kq * 8);
        pv = *(const uint4*)(vB + (size_t)vd * 2048 + vkg * 8);
    }

    char* pslab = smemB + 18944 + w*4352 + qcol*272;   // wave-private P^T row

    for (int t = 0; t < ntiles; ++t) {
        // staged regs -> LDS
        *(uint4*)(smemB + krow*80 + kq*16)          = pk;
        *(uint4*)(smemB + 10240 + vd*272 + vkg*16)  = pv;
        __syncthreads();

        // prefetch next tile (stays outstanding under compute)
        if (t + 1 < ntiles) {
            const int nb = (t + 1) << 7;
            pk = *(const uint4*)(kB + (size_t)(nb + krow) * 32 + kq * 8);
            pv = *(const uint4*)(vB + (size_t)vd * 2048 + nb + vkg * 8);
        }

        const int base2 = t << 7;
        const bool full = (base2 + 128 <= nv);   // block-uniform

        // GEMM1: S^T = K_tile · Q^T (8 subtiles of 16 keys)
        floatx4 sa[8];
        #pragma unroll
        for (int s = 0; s < 8; ++s) {
            const short8 ka = *(const short8*)(smemB + (s*16 + qcol)*80 + quad*16);
            sa[s] = __builtin_amdgcn_mfma_f32_16x16x32_bf16(ka, qfrag, cinit, 0, 0, 0);
        }

        // exp2 (+ tail-select on last tile) + pack P^T into wave-private slab
        #pragma unroll
        for (int s = 0; s < 8; ++s) {
            float p0 = __builtin_amdgcn_exp2f(sa[s][0]);
            float p1 = __builtin_amdgcn_exp2f(sa[s][1]);
            float p2 = __builtin_amdgcn_exp2f(sa[s][2]);
            float p3 = __builtin_amdgcn_exp2f(sa[s][3]);
            if (!full) {
                const int kg = base2 + s*16 + quad*4;
                p0 = (kg     < nv) ? p0 : 0.f;
                p1 = (kg + 1 < nv) ? p1 : 0.f;
                p2 = (kg + 2 < nv) ? p2 : 0.f;
                p3 = (kg + 3 < nv) ? p3 : 0.f;
            }
            lsum += (p0 + p1) + (p2 + p3);
            *(uint2*)(pslab + s*32 + quad*8) = make_uint2(pkbf(p0, p1), pkbf(p2, p3));
        }

        // GEMM2: O^T += V^T_tile · P (4 K=32 chunks x 2 dim-halves)
        #pragma unroll
        for (int kk = 0; kk < 4; ++kk) {
            const short8 pf = *(const short8*)(pslab + kk*64 + quad*16);
            const short8 va = *(const short8*)(smemB + 10240 + qcol*272 + kk*64 + quad*16);
            const short8 vb = *(const short8*)(smemB + 10240 + (16+qcol)*272 + kk*64 + quad*16);
            oacc0 = __builtin_amdgcn_mfma_f32_16x16x32_bf16(va, pf, oacc0, 0, 0, 0);
            oacc1 = __builtin_amdgcn_mfma_f32_16x16x32_bf16(vb, pf, oacc1, 0, 0, 0);
        }
        __syncthreads();
    }

    // ---- epilogue: merge O^T frags + l partials (overlay sK/sVT region)
    {
        float* mrow = smemF + (w*16 + qcol) * 36;
        #pragma unroll
        for (int r = 0; r < 4; ++r) {
            mrow[quad*4 + r]      = oacc0[r];
            mrow[16 + quad*4 + r] = oacc1[r];
        }
        mrow[32 + quad] = lsum;
    }
    __syncthreads();

    if (tid < 128) {
        const float* mrow = smemF + tid * 36;
        const float ll = mrow[32] + mrow[33] + mrow[34] + mrow[35];
        const float inv = (ll > 0.f) ? 1.0f / ll : 0.f;   // never NaN
        const size_t grow = (size_t)bb * LQ + qbase + tid;
        float x[32];
        {
            const float4* qp = ques + grow * 8;
            #pragma unroll
            for (int t = 0; t < 8; ++t) {
                float4 u = qp[t];
                x[t*4+0] = u.x; x[t*4+1] = u.y; x[t*4+2] = u.z; x[t*4+3] = u.w;
            }
        }
        float m = 0.f;
        #pragma unroll
        for (int d = 0; d < 32; ++d) { x[d] = mrow[d] * inv + x[d]; m += x[d]; }
        m *= (1.f / 32.f);
        float v = 0.f;
        #pragma unroll
        for (int d = 0; d < 32; ++d) { float tt = x[d] - m; v += tt * tt; }
        v *= (1.f / 32.f);
        const float r = rsqrtf(v + EPSF);
        float y[32];
        #pragma unroll
        for (int d = 0; d < 32; ++d) y[d] = (x[d] - m) * r * go[d] + bo[d];
        float4* orow = (float4*)(out + grow * 32);
        #pragma unroll
        for (int j = 0; j < 8; ++j)
            orow[j] = make_float4(y[j*4], y[j*4+1], y[j*4+2], y[j*4+3]);
    }
}

// ---------------------------------------------------------------------------
extern "C" void kernel_launch(void* const* d_in, const int* in_sizes, int n_in,
                              void* d_out, int out_size, void* d_ws, size_t ws_size,
                              hipStream_t stream) {
    (void)in_sizes; (void)n_in; (void)out_size; (void)ws_size;
    const float4* vals = (const float4*)d_in[0];
    const float4* keys = (const float4*)d_in[1];
    const float4* ques = (const float4*)d_in[2];
    const void*   key_mask = d_in[3];
    const float4* Wv = (const float4*)d_in[4];
    const float4* Wk = (const float4*)d_in[5];
    const float4* Wq = (const float4*)d_in[6];
    const float* gk = (const float*)d_in[7];
    const float* bk = (const float*)d_in[8];
    const float* gq = (const float*)d_in[9];
    const float* bq = (const float*)d_in[10];
    const float* go = (const float*)d_in[11];
    const float* bo = (const float*)d_in[12];
    float* out = (float*)d_out;

    char* ws = (char*)d_ws;
    int*            counts = (int*)ws;
    unsigned short* kbf    = (unsigned short*)(ws + 512);
    unsigned short* vTb    = (unsigned short*)(ws + 512 + (size_t)NB*2048*32*2);

    hipMemsetAsync(counts, 0, NB * sizeof(int), stream);

    proj_kv_kernel<<<dim3((NB * LK) / 256), 256, 0, stream>>>(
        vals, keys, key_mask, Wv, Wk, gk, bk, counts, kbf, vTb);

    attn_kernel<<<dim3(LQ / 128, NB), 512, 0, stream>>>(
        kbf, vTb, counts, ques, Wq, gq, bq, go, bo, out);
}

// Round 12
// 136.986 us; speedup vs baseline: 1.0971x; 1.0971x over previous
//
#include <hip/hip_runtime.h>
#include <hip/hip_bf16.h>

#define NB   32
#define LQ   2048
#define LK   2048
#define EPSF 1e-5f
// p = exp2(dot(q_scaled, k) - C_L2E); scale = log2(e)/sqrt(20), C = 5*log2(e)
#define SCALE_L2E 0.32260327f
#define C_L2E     7.2134752f

// mask encodings (detected per-block from byte signatures)
#define MASK_I32  0
#define MASK_B8   1
#define MASK_BF16 2
#define MASK_F32  3

typedef __attribute__((ext_vector_type(8))) short  short8;   // 8 bf16 = 4 VGPR
typedef __attribute__((ext_vector_type(4))) float  floatx4;  // MFMA C/D

__device__ __forceinline__ unsigned short f2b(float f) {
    union { float f; unsigned int i; } c; c.f = f;
    unsigned int x = c.i;
    return (unsigned short)((x + 0x7FFFu + ((x >> 16) & 1u)) >> 16);  // RNE
}
// packed f32x2 -> bf16x2 (v_cvt_pk_bf16_f32 on gfx950, RNE)
__device__ __forceinline__ unsigned int pkbf(float a, float b) {
    __hip_bfloat162 h = __float22bfloat162_rn(make_float2(a, b));
    union { __hip_bfloat162 h; unsigned int u; } c; c.h = h; return c.u;
}

__device__ __forceinline__ int mask_nz(const void* m, int g, int enc) {
    switch (enc) {
        case MASK_B8:   return ((const unsigned char*)m)[g]  != 0;
        case MASK_BF16: return ((const unsigned short*)m)[g] != 0;
        case MASK_F32:  return ((const unsigned int*)m)[g]   != 0;
        default:        return ((const int*)m)[g]            != 0;
    }
}

// ---------------------------------------------------------------------------
// Kernel 1 (unchanged, verified): k = LN(keys @ Wk^T), v = vals @ Wv^T.
// kbf [B][2048][32] bf16 (20 real + 12 zero); vTb [B][32][2048] bf16.
// ---------------------------------------------------------------------------
__global__ __launch_bounds__(256) void proj_kv_kernel(
    const float4* __restrict__ vals,
    const float4* __restrict__ keys,
    const void*   __restrict__ key_mask,
    const float4* __restrict__ Wv,
    const float4* __restrict__ Wk,
    const float*  __restrict__ gk,
    const float*  __restrict__ bk,
    int*            __restrict__ counts,
    unsigned short* __restrict__ kbf,
    unsigned short* __restrict__ vTb)
{
    __shared__ float smem[1704];
    __shared__ int sc[3];
    float* sWv = smem;
    float* sWk = smem + 1024;
    float* sgk = smem + 1664;
    float* sbk = smem + 1684;
    const int tid = threadIdx.x;
    if (tid < 3) sc[tid] = 0;
    __syncthreads();

    ((float4*)sWv)[tid] = Wv[tid];
    if (tid < 160) ((float4*)sWk)[tid] = Wk[tid];
    if (tid < 20) sgk[tid] = gk[tid];
    if (tid >= 32 && tid < 52) sbk[tid - 32] = bk[tid - 32];
    {
        const unsigned char* mbytes = (const unsigned char*)key_mask;
        int l0 = 0, l1 = 0, l2 = 0;
        for (int i = tid; i < 1024; i += 256) {
            const unsigned char mb = mbytes[i];
            if ((i & 3) == 1 && mb == 0x3Fu) l0++;
            if ((i & 3) == 3 && mb == 0x3Fu) l1++;
            if ((i & 1) == 1 && mb == 0x01u) l2++;
        }
        if (l0) atomicAdd(&sc[0], l0);
        if (l1) atomicAdd(&sc[1], l1);
        if (l2) atomicAdd(&sc[2], l2);
    }
    __syncthreads();
    const int enc = sc[0] ? MASK_BF16 : (sc[1] ? MASK_F32 : (sc[2] ? MASK_B8 : MASK_I32));

    const int g = blockIdx.x * 256 + tid;
    const int b = g >> 11;
    const int lane = tid & 63;

    const int valid = mask_nz(key_mask, g, enc) ? 0 : 1;
    const unsigned long long mb = __ballot(valid);
    const int cnt = __popcll(mb);
    int base = 0;
    if (lane == 0) base = atomicAdd(&counts[b], cnt);
    base = __shfl(base, 0);
    const int slot = base + __popcll(mb & ((1ull << lane) - 1ull));

    float x[32];

    {   // keys -> k proj -> LN -> bf16 padded store
        const float4* kp = keys + (size_t)g * 8;
        #pragma unroll
        for (int t = 0; t < 8; ++t) {
            float4 u = kp[t];
            x[t*4+0] = u.x; x[t*4+1] = u.y; x[t*4+2] = u.z; x[t*4+3] = u.w;
        }
        const float4* wk4 = (const float4*)sWk;
        float kv[20];
        #pragma unroll
        for (int c = 0; c < 20; ++c) {
            float s = 0.f;
            #pragma unroll
            for (int i = 0; i < 8; ++i) {
                float4 ww = wk4[c * 8 + i];
                s = fmaf(x[i*4+0], ww.x, s); s = fmaf(x[i*4+1], ww.y, s);
                s = fmaf(x[i*4+2], ww.z, s); s = fmaf(x[i*4+3], ww.w, s);
            }
            kv[c] = s;
        }
        float m = 0.f;
        #pragma unroll
        for (int c = 0; c < 20; ++c) m += kv[c];
        m *= (1.f / 20.f);
        float v = 0.f;
        #pragma unroll
        for (int c = 0; c < 20; ++c) { float d = kv[c] - m; v += d * d; }
        v *= (1.f / 20.f);
        const float r = rsqrtf(v + EPSF);
        if (valid) {
            unsigned int u[16];
            #pragma unroll
            for (int j = 0; j < 10; ++j) {
                const float t0 = (kv[2*j]   - m) * r * sgk[2*j]   + sbk[2*j];
                const float t1 = (kv[2*j+1] - m) * r * sgk[2*j+1] + sbk[2*j+1];
                u[j] = pkbf(t0, t1);
            }
            #pragma unroll
            for (int j = 10; j < 16; ++j) u[j] = 0u;
            uint4* dst = (uint4*)kbf + (size_t)(b * 2048 + slot) * 4;
            #pragma unroll
            for (int j = 0; j < 4; ++j)
                dst[j] = make_uint4(u[j*4], u[j*4+1], u[j*4+2], u[j*4+3]);
        }
    }

    {   // vals -> v proj -> transposed bf16 store
        const float4* vp = vals + (size_t)g * 8;
        #pragma unroll
        for (int t = 0; t < 8; ++t) {
            float4 u = vp[t];
            x[t*4+0] = u.x; x[t*4+1] = u.y; x[t*4+2] = u.z; x[t*4+3] = u.w;
        }
        if (valid) {
            const float4* wv4 = (const float4*)sWv;
            #pragma unroll
            for (int o = 0; o < 32; ++o) {
                float s = 0.f;
                #pragma unroll
                for (int i = 0; i < 8; ++i) {
                    float4 ww = wv4[o * 8 + i];
                    s = fmaf(x[i*4+0], ww.x, s); s = fmaf(x[i*4+1], ww.y, s);
                    s = fmaf(x[i*4+2], ww.z, s); s = fmaf(x[i*4+3], ww.w, s);
                }
                vTb[((size_t)b * 32 + o) * 2048 + slot] = f2b(s);
            }
        }
    }
}

// ---------------------------------------------------------------------------
// Kernel 2: MFMA flash attention. vs R10: plain __launch_bounds__(512)
// (R11's (512,6) forced VGPR=40 -> scratch spills, WRITE_SIZE 3x) and
// DOUBLE-BUFFERED K/V staging -> 1 barrier/tile instead of 2:
// tile t writes buf (t&1); that buf was last read at tile t-2, and every
// wave passed barrier(t-1) only after finishing compute(t-2) -> safe.
// LDS 72704 B, 2 blocks/CU (145 KB <= 160 KB):
//   sK0 0..10240 | sV0 10240..18944 | sK1 18944..29184 | sV1 29184..37888 |
//   sPT 37888..72704 (8 waves x 16 x 272 B)
// Prologue: Wq/gq/bq in sK0; bf16 Q rows (80 B stride) in sPT region.
// Epilogue merge overlays bytes 0..18432 (buf0) after a post-loop barrier.
// ---------------------------------------------------------------------------
__global__ __launch_bounds__(512) void attn_kernel(
    const unsigned short* __restrict__ kbf,   // [B][2048][32] bf16
    const unsigned short* __restrict__ vTb,   // [B][32][2048] bf16
    const int*    __restrict__ counts,
    const float4* __restrict__ ques,          // [B*LQ*32] f32
    const float4* __restrict__ Wq,
    const float*  __restrict__ gq,
    const float*  __restrict__ bq,
    const float*  __restrict__ go,
    const float*  __restrict__ bo,
    float* __restrict__ out)
{
    __shared__ uint4 smem4[4544];             // 72704 B
    char*  smemB = (char*)smem4;
    float* smemF = (float*)smem4;

    const int tid  = threadIdx.x;
    const int w    = tid >> 6;                // 0..7
    const int lane = tid & 63;
    const int qcol = lane & 15;
    const int quad = lane >> 4;
    const int bb   = blockIdx.y;
    const int qbase = blockIdx.x * 128;

    // ---- prologue: Wq/gq/bq into sK0 region (floats 0..680)
    if (tid < 160) ((float4*)smemF)[tid] = Wq[tid];
    if (tid >= 192 && tid < 212) smemF[640 + tid - 192] = gq[tid - 192];
    if (tid >= 224 && tid < 244) smemF[660 + tid - 224] = bq[tid - 224];
    __syncthreads();

    // ---- q proj + LN + scale -> bf16 rows (20 real + 12 zero) in sPT region
    if (tid < 128) {
        const size_t grow = (size_t)bb * LQ + qbase + tid;
        float x[32];
        const float4* qp = ques + grow * 8;
        #pragma unroll
        for (int t = 0; t < 8; ++t) {
            float4 u = qp[t];
            x[t*4+0] = u.x; x[t*4+1] = u.y; x[t*4+2] = u.z; x[t*4+3] = u.w;
        }
        float qv[20];
        #pragma unroll
        for (int c = 0; c < 20; ++c) {
            float s = 0.f;
            #pragma unroll
            for (int i = 0; i < 32; ++i) s = fmaf(x[i], smemF[c*32 + i], s);
            qv[c] = s;
        }
        float m = 0.f;
        #pragma unroll
        for (int c = 0; c < 20; ++c) m += qv[c];
        m *= (1.f / 20.f);
        float v = 0.f;
        #pragma unroll
        for (int c = 0; c < 20; ++c) { float d = qv[c] - m; v += d * d; }
        v *= (1.f / 20.f);
        const float r = rsqrtf(v + EPSF);
        unsigned int u[16];
        #pragma unroll
        for (int j = 0; j < 10; ++j) {
            const float t0 = ((qv[2*j]   - m) * r * smemF[640+2*j]   + smemF[660+2*j])   * SCALE_L2E;
            const float t1 = ((qv[2*j+1] - m) * r * smemF[640+2*j+1] + smemF[660+2*j+1]) * SCALE_L2E;
            u[j] = pkbf(t0, t1);
        }
        #pragma unroll
        for (int j = 10; j < 16; ++j) u[j] = 0u;
        uint4* dst = (uint4*)(smemB + 37888 + tid * 80);
        #pragma unroll
        for (int j = 0; j < 4; ++j)
            dst[j] = make_uint4(u[j*4], u[j*4+1], u[j*4+2], u[j*4+3]);
    }
    __syncthreads();

    // loop-invariant B1 fragment: Q[q = w*16+qcol][k = quad*8..+7]
    const short8 qfrag = *(const short8*)(smemB + 37888 + (w*16 + qcol)*80 + quad*16);
    __syncthreads();   // prologue regions may now be overwritten

    const int nv = counts[bb];
    const int ntiles = (nv + 127) >> 7;
    const floatx4 cinit = { -C_L2E, -C_L2E, -C_L2E, -C_L2E };
    floatx4 oacc0 = {0.f, 0.f, 0.f, 0.f};
    floatx4 oacc1 = {0.f, 0.f, 0.f, 0.f};
    float lsum = 0.f;

    const unsigned short* kB = kbf + (size_t)bb * 2048 * 32;
    const unsigned short* vB = vTb + (size_t)bb * 32 * 2048;

    // staging thread mapping (512 threads, 16 B each for K and V^T)
    const int krow = tid >> 2, kq = tid & 3;     // K: 128 rows x 64 B
    const int vd   = tid >> 4, vkg = tid & 15;   // V^T: 32 dims x 256 B

    // prefetch tile 0
    uint4 pk, pv;
    if (ntiles > 0) {
        pk = *(const uint4*)(kB + (size_t)krow * 32 + kq * 8);
        pv = *(const uint4*)(vB + (size_t)vd * 2048 + vkg * 8);
    }

    char* pslab = smemB + 37888 + w*4352 + qcol*272;   // wave-private P^T row

    for (int t = 0; t < ntiles; ++t) {
        const int kbase = (t & 1) ? 18944 : 0;         // this tile's K buf
        const int vbase = (t & 1) ? 29184 : 10240;     // this tile's V buf

        // staged regs -> LDS (buf t&1; last read at tile t-2, ordered by
        // barrier(t-1) which every wave passed only after compute(t-2))
        *(uint4*)(smemB + kbase + krow*80 + kq*16)  = pk;
        *(uint4*)(smemB + vbase + vd*272 + vkg*16)  = pv;

        // prefetch next tile (stays outstanding under compute)
        if (t + 1 < ntiles) {
            const int nb = (t + 1) << 7;
            pk = *(const uint4*)(kB + (size_t)(nb + krow) * 32 + kq * 8);
            pv = *(const uint4*)(vB + (size_t)vd * 2048 + nb + vkg * 8);
        }
        __syncthreads();   // the ONLY barrier per tile

        const int base2 = t << 7;
        const bool full = (base2 + 128 <= nv);   // block-uniform

        // GEMM1: S^T = K_tile · Q^T (8 subtiles of 16 keys)
        floatx4 sa[8];
        #pragma unroll
        for (int s = 0; s < 8; ++s) {
            const short8 ka = *(const short8*)(smemB + kbase + (s*16 + qcol)*80 + quad*16);
            sa[s] = __builtin_amdgcn_mfma_f32_16x16x32_bf16(ka, qfrag, cinit, 0, 0, 0);
        }

        // exp2 (+ tail-select on last tile) + pack P^T into wave-private slab
        #pragma unroll
        for (int s = 0; s < 8; ++s) {
            float p0 = __builtin_amdgcn_exp2f(sa[s][0]);
            float p1 = __builtin_amdgcn_exp2f(sa[s][1]);
            float p2 = __builtin_amdgcn_exp2f(sa[s][2]);
            float p3 = __builtin_amdgcn_exp2f(sa[s][3]);
            if (!full) {
                const int kg = base2 + s*16 + quad*4;
                p0 = (kg     < nv) ? p0 : 0.f;
                p1 = (kg + 1 < nv) ? p1 : 0.f;
                p2 = (kg + 2 < nv) ? p2 : 0.f;
                p3 = (kg + 3 < nv) ? p3 : 0.f;
            }
            lsum += (p0 + p1) + (p2 + p3);
            *(uint2*)(pslab + s*32 + quad*8) = make_uint2(pkbf(p0, p1), pkbf(p2, p3));
        }

        // GEMM2: O^T += V^T_tile · P (4 K=32 chunks x 2 dim-halves)
        #pragma unroll
        for (int kk = 0; kk < 4; ++kk) {
            const short8 pf = *(const short8*)(pslab + kk*64 + quad*16);
            const short8 va = *(const short8*)(smemB + vbase + qcol*272 + kk*64 + quad*16);
            const short8 vb = *(const short8*)(smemB + vbase + (16+qcol)*272 + kk*64 + quad*16);
            oacc0 = __builtin_amdgcn_mfma_f32_16x16x32_bf16(va, pf, oacc0, 0, 0, 0);
            oacc1 = __builtin_amdgcn_mfma_f32_16x16x32_bf16(vb, pf, oacc1, 0, 0, 0);
        }
        // no post-compute barrier: dbuf makes next tile's staging safe
    }
    __syncthreads();   // all compute done before merge overlays buf0

    // ---- epilogue: merge O^T frags + l partials (overlay bytes 0..18432)
    {
        float* mrow = smemF + (w*16 + qcol) * 36;
        #pragma unroll
        for (int r = 0; r < 4; ++r) {
            mrow[quad*4 + r]      = oacc0[r];
            mrow[16 + quad*4 + r] = oacc1[r];
        }
        mrow[32 + quad] = lsum;
    }
    __syncthreads();

    if (tid < 128) {
        const float* mrow = smemF + tid * 36;
        const float ll = mrow[32] + mrow[33] + mrow[34] + mrow[35];
        const float inv = (ll > 0.f) ? 1.0f / ll : 0.f;   // never NaN
        const size_t grow = (size_t)bb * LQ + qbase + tid;
        float x[32];
        {
            const float4* qp = ques + grow * 8;
            #pragma unroll
            for (int t = 0; t < 8; ++t) {
                float4 u = qp[t];
                x[t*4+0] = u.x; x[t*4+1] = u.y; x[t*4+2] = u.z; x[t*4+3] = u.w;
            }
        }
        float m = 0.f;
        #pragma unroll
        for (int d = 0; d < 32; ++d) { x[d] = mrow[d] * inv + x[d]; m += x[d]; }
        m *= (1.f / 32.f);
        float v = 0.f;
        #pragma unroll
        for (int d = 0; d < 32; ++d) { float tt = x[d] - m; v += tt * tt; }
        v *= (1.f / 32.f);
        const float r = rsqrtf(v + EPSF);
        float y[32];
        #pragma unroll
        for (int d = 0; d < 32; ++d) y[d] = (x[d] - m) * r * go[d] + bo[d];
        float4* orow = (float4*)(out + grow * 32);
        #pragma unroll
        for (int j = 0; j < 8; ++j)
            orow[j] = make_float4(y[j*4], y[j*4+1], y[j*4+2], y[j*4+3]);
    }
}

// ---------------------------------------------------------------------------
extern "C" void kernel_launch(void* const* d_in, const int* in_sizes, int n_in,
                              void* d_out, int out_size, void* d_ws, size_t ws_size,
                              hipStream_t stream) {
    (void)in_sizes; (void)n_in; (void)out_size; (void)ws_size;
    const float4* vals = (const float4*)d_in[0];
    const float4* keys = (const float4*)d_in[1];
    const float4* ques = (const float4*)d_in[2];
    const void*   key_mask = d_in[3];
    const float4* Wv = (const float4*)d_in[4];
    const float4* Wk = (const float4*)d_in[5];
    const float4* Wq = (const float4*)d_in[6];
    const float* gk = (const float*)d_in[7];
    const float* bk = (const float*)d_in[8];
    const float* gq = (const float*)d_in[9];
    const float* bq = (const float*)d_in[10];
    const float* go = (const float*)d_in[11];
    const float* bo = (const float*)d_in[12];
    float* out = (float*)d_out;

    char* ws = (char*)d_ws;
    int*            counts = (int*)ws;
    unsigned short* kbf    = (unsigned short*)(ws + 512);
    unsigned short* vTb    = (unsigned short*)(ws + 512 + (size_t)NB*2048*32*2);

    hipMemsetAsync(counts, 0, NB * sizeof(int), stream);

    proj_kv_kernel<<<dim3((NB * LK) / 256), 256, 0, stream>>>(
        vals, keys, key_mask, Wv, Wk, gk, bk, counts, kbf, vTb);

    attn_kernel<<<dim3(LQ / 128, NB), 512, 0, stream>>>(
        kbf, vTb, counts, ques, Wq, gq, bq, go, bo, out);
}